// Round 3
// baseline (933.200 us; speedup 1.0000x reference)
//
#include <hip/hip_runtime.h>
#include <hip/hip_bf16.h>
#include <stdint.h>
#include <stddef.h>

#define TT 128
#define BB 16
#define VV 50000
#define DD 300
#define HH 256
#define WW 5
#define MM (TT*BB)      // 2048
#define NPAD 50176      // padded N for W2^T storage

typedef __bf16 bf16x8 __attribute__((ext_vector_type(8)));
typedef float  f32x16 __attribute__((ext_vector_type(16)));

typedef const __attribute__((address_space(1))) uint32_t as1_u32;
typedef __attribute__((address_space(3))) uint32_t       as3_u32;

static __device__ __forceinline__ ushort rne_bf16(float v) {
  uint32_t u = __builtin_bit_cast(uint32_t, v);
  u += 0x7fffu + ((u >> 16) & 1u);
  return (ushort)(u >> 16);
}
static __device__ __forceinline__ float bf16_to_f(ushort h) {
  return __builtin_bit_cast(float, (uint32_t)h << 16);
}

// ---------------------------------------------------------------------------
// k2: W2 [256][50000] f32  ->  W2T_hi / W2T_lo [NPAD][256] bf16 (hi/lo split)
// LDS transpose so global reads (along n) AND writes (along k) are coalesced.
// Granule(16B)-XOR swizzle on LDS store+load (same involution both sides).
// ---------------------------------------------------------------------------
__global__ __launch_bounds__(256, 1)
void k2_w2t(const float* __restrict__ W2, ushort* __restrict__ tHi,
            ushort* __restrict__ tLo) {
  __shared__ ushort Lh[64][256];   // 32 KB
  __shared__ ushort Ll[64][256];   // 32 KB
  const int tid = threadIdx.x;
  const int n0  = blockIdx.x * 64;
  const int nl  = tid & 63;        // n within block
  const int gq  = tid >> 6;        // granule quarter 0..3
  const int n   = n0 + nl;

  // read (n-coalesced) + split + swizzled LDS store
  for (int c = 0; c < 8; ++c) {
    const int g = c * 4 + gq;      // granule 0..31 (8 k-elems each)
    alignas(16) ushort h8[8], l8[8];
#pragma unroll
    for (int e = 0; e < 8; ++e) {
      int k = g * 8 + e;
      float v = (n < VV) ? W2[(size_t)k * VV + n] : 0.f;
      ushort hb = rne_bf16(v);
      h8[e] = hb;
      l8[e] = rne_bf16(v - bf16_to_f(hb));
    }
    const int gs = g ^ (nl & 31);
    *reinterpret_cast<uint4*>(&Lh[nl][gs * 8]) = *reinterpret_cast<const uint4*>(h8);
    *reinterpret_cast<uint4*>(&Ll[nl][gs * 8]) = *reinterpret_cast<const uint4*>(l8);
  }
  __syncthreads();

  // swizzled LDS load + contiguous global store (1KB per wave)
  const int gl  = tid & 31;        // output granule
  const int nr0 = tid >> 5;        // 0..7
  for (int p = 0; p < 8; ++p) {
    int nr = p * 8 + nr0;          // row 0..63
    int gs = gl ^ (nr & 31);
    uint4 h = *reinterpret_cast<const uint4*>(&Lh[nr][gs * 8]);
    uint4 l = *reinterpret_cast<const uint4*>(&Ll[nr][gs * 8]);
    size_t o = ((size_t)(n0 + nr) << 8) + (size_t)gl * 8;
    *reinterpret_cast<uint4*>(tHi + o) = h;
    *reinterpret_cast<uint4*>(tLo + o) = l;
  }
}

// ---------------------------------------------------------------------------
// k1: gather ctx embeddings (token id 0 for t<0 padding), x@W1+b1, tanh,
//     write h as bf16 hi/lo [2048][256].
// 512 threads: 8 positions/block, x in LDS (96KB), K=3000 split in halves.
// ---------------------------------------------------------------------------
__global__ __launch_bounds__(512, 1)
void k1_embed_gemm1(const int* __restrict__ text, const float* __restrict__ Ef,
                    const float* __restrict__ Eu, const float* __restrict__ W1,
                    const float* __restrict__ b1, ushort* __restrict__ hHi,
                    ushort* __restrict__ hLo) {
  __shared__ float X[8][3000];    // 96000 B
  __shared__ float Red[8][256];   // 8192 B
  __shared__ int   Toks[8][5];
  const int tid = threadIdx.x;
  const int pbase = blockIdx.x * 8;

  if (tid < 40) {
    int p = tid / 5, w = tid - p * 5;
    int pg = pbase + p;
    int t = pg >> 4, b = pg & 15;
    int tw = t - WW + w;
    Toks[p][w] = (tw >= 0) ? text[tw * BB + b] : 0;
  }
  __syncthreads();

  // gather: 8 pos * 10 slots (w-major, [fixed,upd] per w) * 300
  for (int e = tid; e < 8 * 3000; e += 512) {
    int p = e / 3000; int rem = e - p * 3000;
    int slot = rem / 300; int d = rem - slot * 300;
    const float* tab = (slot & 1) ? Eu : Ef;
    X[p][rem] = tab[(size_t)Toks[p][slot >> 1] * DD + d];
  }
  __syncthreads();

  const int j  = tid & 255;
  const int kh = tid >> 8;  // 0 or 1 -> k half
  float acc[8] = {0.f, 0.f, 0.f, 0.f, 0.f, 0.f, 0.f, 0.f};
  const int kbeg = kh * 1500;
  for (int k = kbeg; k < kbeg + 1500; k += 4) {
    float w0  = W1[(size_t)(k + 0) * HH + j];
    float w1v = W1[(size_t)(k + 1) * HH + j];
    float w2v = W1[(size_t)(k + 2) * HH + j];
    float w3v = W1[(size_t)(k + 3) * HH + j];
#pragma unroll
    for (int p = 0; p < 8; ++p) {
      float4 xv = *reinterpret_cast<const float4*>(&X[p][k]);
      acc[p] = fmaf(xv.x, w0, acc[p]);
      acc[p] = fmaf(xv.y, w1v, acc[p]);
      acc[p] = fmaf(xv.z, w2v, acc[p]);
      acc[p] = fmaf(xv.w, w3v, acc[p]);
    }
  }
  if (kh == 1) {
#pragma unroll
    for (int p = 0; p < 8; ++p) Red[p][j] = acc[p];
  }
  __syncthreads();
  if (kh == 0) {
#pragma unroll
    for (int p = 0; p < 8; ++p) {
      float s = acc[p] + Red[p][j] + b1[j];
      float th = tanhf(s);
      ushort hb = rne_bf16(th);
      ushort lb = rne_bf16(th - bf16_to_f(hb));
      hHi[(size_t)(pbase + p) * HH + j] = hb;
      hLo[(size_t)(pbase + p) * HH + j] = lb;
    }
  }
}

// ---------------------------------------------------------------------------
// k3: logits[2048][50000] = h @ W2 + b2 via split-bf16 MFMA (3 terms).
// Block: 512 thr = 8 waves (4m x 2n). BM=256, BN=128, full K=256 in LDS.
// B staged with global_load_lds(16B), XOR-swizzled SOURCE granule (G21),
// linear LDS dest; reads apply the same XOR. 1-D grid with XCD grouping:
// all 8 m-blocks of one n-slice land on the same XCD -> B fetched once.
// ---------------------------------------------------------------------------
__global__ __launch_bounds__(512, 1)
void k3_gemm2(const ushort* __restrict__ hHi, const ushort* __restrict__ hLo,
              const ushort* __restrict__ bHiG, const ushort* __restrict__ bLoG,
              const float* __restrict__ b2, float* __restrict__ out) {
  __shared__ ushort Bsh[2][128 * 256];  // 128 KB
  const int tid  = threadIdx.x;
  const int lane = tid & 63;
  const int wid  = tid >> 6;      // 0..7
  const int wm   = wid & 3;       // wave m index (0..3)
  const int wn   = wid >> 2;      // wave n index (0..1)

  // XCD-grouped decomposition of 3128 blocks = 8 m x 391 n.
  // Main: bid = grp*64 + j*8 + xcd  -> n = grp*8+xcd (same XCD), m = j.
  const int bid = blockIdx.x;
  int m_idx, n_idx;
  if (bid < 3072) {
    n_idx = (bid >> 6) * 8 + (bid & 7);
    m_idx = (bid >> 3) & 7;
  } else {
    int local = bid - 3072;       // 0..55 -> 7 n x 8 m tail
    n_idx = 384 + local % 7;
    m_idx = local / 7;
  }
  const int m0 = m_idx * 256;
  const int n0 = n_idx * 128;

  // ---- stage B hi/lo into LDS ----
  {
    const int r = tid >> 5;          // 0..15
    const int p = tid & 31;          // 16B granule
    const int wave_off = wid << 10;  // wave-uniform LDS offset
    char* baseH = (char*)(&Bsh[0][0]);
    char* baseL = (char*)(&Bsh[1][0]);
#pragma unroll
    for (int i = 0; i < 8; ++i) {
      int row = (i << 4) + r;
      int g = p ^ (row & 31);        // pre-swizzled source granule
      size_t soff = (((size_t)(n0 + row)) << 8) + ((size_t)g << 3);
      const ushort* sh = bHiG + soff;
      const ushort* sl = bLoG + soff;
      char* dh = baseH + (i << 13) + wave_off;
      char* dl = baseL + (i << 13) + wave_off;
      __builtin_amdgcn_global_load_lds((as1_u32*)sh, (as3_u32*)dh, 16, 0, 0);
      __builtin_amdgcn_global_load_lds((as1_u32*)sl, (as3_u32*)dl, 16, 0, 0);
    }
  }
  __syncthreads();

  // ---- compute ----
  const int arow = lane & 31;   // A row within 32 / B col within 32
  const int kg   = lane >> 5;   // k-group (0/1)
  const size_t aoff = (size_t)(m0 + wm * 64 + arow) * 256 + kg * 8;
  const ushort* aHb = hHi + aoff;
  const ushort* aLb = hLo + aoff;

  f32x16 acc[2][2] = {};

#pragma unroll
  for (int ks = 0; ks < 16; ++ks) {
    bf16x8 aH[2], aL[2], bH[2], bL[2];
#pragma unroll
    for (int fm = 0; fm < 2; ++fm) {
      size_t o = (size_t)fm * 32 * 256 + ks * 16;
      aH[fm] = *reinterpret_cast<const bf16x8*>(aHb + o);
      aL[fm] = *reinterpret_cast<const bf16x8*>(aLb + o);
    }
#pragma unroll
    for (int fn = 0; fn < 2; ++fn) {
      int nl = wn * 64 + fn * 32 + arow;
      int g = (ks * 2 + kg) ^ (nl & 31);
      int off = nl * 256 + g * 8;
      bH[fn] = *reinterpret_cast<const bf16x8*>(&Bsh[0][off]);
      bL[fn] = *reinterpret_cast<const bf16x8*>(&Bsh[1][off]);
    }
#pragma unroll
    for (int fm = 0; fm < 2; ++fm)
#pragma unroll
      for (int fn = 0; fn < 2; ++fn) {
        acc[fm][fn] = __builtin_amdgcn_mfma_f32_32x32x16_bf16(aH[fm], bH[fn], acc[fm][fn], 0, 0, 0);
        acc[fm][fn] = __builtin_amdgcn_mfma_f32_32x32x16_bf16(aH[fm], bL[fn], acc[fm][fn], 0, 0, 0);
        acc[fm][fn] = __builtin_amdgcn_mfma_f32_32x32x16_bf16(aL[fm], bH[fn], acc[fm][fn], 0, 0, 0);
      }
  }

  // ---- epilogue: + b2, guarded store ----
#pragma unroll
  for (int fn = 0; fn < 2; ++fn) {
    int col = n0 + wn * 64 + fn * 32 + arow;
    bool ok = col < VV;
    float bias = ok ? b2[col] : 0.f;
#pragma unroll
    for (int fm = 0; fm < 2; ++fm) {
      int mbase = m0 + wm * 64 + fm * 32 + 4 * kg;
#pragma unroll
      for (int rg = 0; rg < 16; ++rg) {
        int rr = (rg & 3) + 8 * (rg >> 2);
        if (ok) out[(size_t)(mbase + rr) * VV + col] = acc[fm][fn][rg] + bias;
      }
    }
  }
}

// ---------------------------------------------------------------------------
extern "C" void kernel_launch(void* const* d_in, const int* in_sizes, int n_in,
                              void* d_out, int out_size, void* d_ws, size_t ws_size,
                              hipStream_t stream) {
  (void)in_sizes; (void)n_in; (void)out_size; (void)ws_size;
  const int*   text = (const int*)d_in[0];
  const float* Ef   = (const float*)d_in[1];
  const float* Eu   = (const float*)d_in[2];
  const float* W1   = (const float*)d_in[3];
  const float* b1   = (const float*)d_in[4];
  const float* W2   = (const float*)d_in[5];
  const float* b2   = (const float*)d_in[6];
  float* out = (float*)d_out;

  // workspace layout (~53.4 MB)
  ushort* w2tHi = (ushort*)d_ws;
  ushort* w2tLo = w2tHi + (size_t)NPAD * 256;
  ushort* hHi   = w2tLo + (size_t)NPAD * 256;
  ushort* hLo   = hHi + (size_t)MM * 256;

  hipLaunchKernelGGL(k2_w2t, dim3(NPAD / 64), dim3(256), 0, stream, W2, w2tHi, w2tLo);
  hipLaunchKernelGGL(k1_embed_gemm1, dim3(MM / 8), dim3(512), 0, stream,
                     text, Ef, Eu, W1, b1, hHi, hLo);
  hipLaunchKernelGGL(k3_gemm2, dim3(8 * 391), dim3(512), 0, stream,
                     hHi, hLo, w2tHi, w2tLo, b2, out);
}